// Round 1
// baseline (587.317 us; speedup 1.0000x reference)
//
#include <hip/hip_runtime.h>
#include <hip/hip_bf16.h>

typedef __bf16 bf16;
typedef __attribute__((ext_vector_type(8))) __bf16 bf16x8;
typedef __attribute__((ext_vector_type(4))) __bf16 bf16x4;
typedef __attribute__((ext_vector_type(4))) float f32x4;

// ---------------------------------------------------------------- constants
#define B_SZ 2
#define S_SZ 2048
#define D_SZ 2048
#define H_SZ 32
#define KV_SZ 8
#define HD_SZ 64
#define M_SZ (B_SZ * S_SZ)   // 4096

// ---------------------------------------------------------------- f32 -> bf16
__global__ void cvt_f32_bf16(const float* __restrict__ in, bf16* __restrict__ out, int n4) {
    int i = blockIdx.x * blockDim.x + threadIdx.x;
    if (i >= n4) return;
    float4 v = ((const float4*)in)[i];
    bf16x4 o;
    o.x = (bf16)v.x; o.y = (bf16)v.y; o.z = (bf16)v.z; o.w = (bf16)v.w;
    ((bf16x4*)out)[i] = o;
}

// ---------------------------------------------------------------- NT GEMM
// C[m,n] = sum_k A[m,k] * Bw[n,k]   (both row-major, K contiguous)
// mode 0: Co[m*N + n] = fp32
// mode 1: RoPE epilogue, bf16 store to ((b*Hn + h)*S + s)*64 + d, Hn = N/64
// mode 2: bf16 store transposed: ((b*KVn + kv)*64 + d)*S + s, KVn = N/64
#define LDT 56   // LDS row stride (elems): 112 B = 16*7, 2-way-conflict-free

__global__ __launch_bounds__(256)
void gemm_bt(const bf16* __restrict__ A, const bf16* __restrict__ Bw,
             float* __restrict__ Co, bf16* __restrict__ Cb,
             const float* __restrict__ cosp, const float* __restrict__ sinp,
             int M, int N, int K, int mode)
{
    __shared__ bf16 As[128 * LDT];
    __shared__ bf16 Bs[128 * LDT];
    const int tid  = threadIdx.x;
    const int lane = tid & 63;
    const int wave = tid >> 6;
    const int waveM = wave >> 1, waveN = wave & 1;
    const int c = lane & 15, quad = lane >> 4;
    const int rowBase = blockIdx.y * 128;
    const int colBase = blockIdx.x * 128;

    const int sRow = tid >> 2;        // 0..63
    const int sCol = (tid & 3) * 8;   // 0,8,16,24

    f32x4 acc[4][4] = {};

    const bf16* Ag = A  + (size_t)(rowBase + sRow) * K + sCol;
    const bf16* Bg = Bw + (size_t)(colBase + sRow) * K + sCol;

    for (int k0 = 0; k0 < K; k0 += 32) {
        uint4 a0 = *(const uint4*)(Ag + k0);
        uint4 a1 = *(const uint4*)(Ag + (size_t)64 * K + k0);
        uint4 b0 = *(const uint4*)(Bg + k0);
        uint4 b1 = *(const uint4*)(Bg + (size_t)64 * K + k0);
        *(uint4*)(As + sRow * LDT + sCol)        = a0;
        *(uint4*)(As + (sRow + 64) * LDT + sCol) = a1;
        *(uint4*)(Bs + sRow * LDT + sCol)        = b0;
        *(uint4*)(Bs + (sRow + 64) * LDT + sCol) = b1;
        __syncthreads();

        bf16x8 af[4], bfr[4];
#pragma unroll
        for (int mi = 0; mi < 4; mi++)
            af[mi] = *(const bf16x8*)(As + (waveM * 64 + mi * 16 + c) * LDT + quad * 8);
#pragma unroll
        for (int ni = 0; ni < 4; ni++)
            bfr[ni] = *(const bf16x8*)(Bs + (waveN * 64 + ni * 16 + c) * LDT + quad * 8);
#pragma unroll
        for (int mi = 0; mi < 4; mi++)
#pragma unroll
            for (int ni = 0; ni < 4; ni++)
                acc[mi][ni] = __builtin_amdgcn_mfma_f32_16x16x32_bf16(af[mi], bfr[ni], acc[mi][ni], 0, 0, 0);
        __syncthreads();
    }

    const int mBase = rowBase + waveM * 64;
    const int nBase = colBase + waveN * 64;

    if (mode == 0) {
#pragma unroll
        for (int mi = 0; mi < 4; mi++)
#pragma unroll
            for (int ni = 0; ni < 4; ni++) {
                int col = nBase + ni * 16 + c;
#pragma unroll
                for (int r = 0; r < 4; r++) {
                    int row = mBase + mi * 16 + quad * 4 + r;
                    Co[(size_t)row * N + col] = acc[mi][ni][r];
                }
            }
    } else if (mode == 1) {
        // RoPE: wave's 64 cols = exactly one head (nBase multiple of 64)
        const int Hn = N >> 6;
        const int h  = nBase >> 6;
#pragma unroll
        for (int mi = 0; mi < 4; mi++) {
#pragma unroll
            for (int r = 0; r < 4; r++) {
                int row = mBase + mi * 16 + quad * 4 + r;
                int b = row >> 11;           // S = 2048
                int s = row & 2047;
                const float* cr = cosp + (size_t)s * 32;
                const float* sr = sinp + (size_t)s * 32;
                size_t base = ((size_t)(b * Hn + h) * S_SZ + s) * 64;
#pragma unroll
                for (int ni = 0; ni < 2; ni++) {
                    int d = ni * 16 + c;          // 0..31
                    float x1 = acc[mi][ni][r];
                    float x2 = acc[mi][ni + 2][r];
                    float cv = cr[d], sv = sr[d];
                    Cb[base + d]      = (bf16)(x1 * cv - x2 * sv);
                    Cb[base + d + 32] = (bf16)(x1 * sv + x2 * cv);
                }
            }
        }
    } else {
        // mode 2: V transposed store (b, kv, d, s)
        const int KVn = N >> 6;
        const int kvh = nBase >> 6;
        const int b   = mBase >> 11;
        const int s0  = mBase & 2047;
#pragma unroll
        for (int ni = 0; ni < 4; ni++) {
            int d = ni * 16 + c;
            size_t base = ((size_t)(b * KVn + kvh) * 64 + d) * (size_t)S_SZ;
#pragma unroll
            for (int mi = 0; mi < 4; mi++) {
                int s = s0 + mi * 16 + quad * 4;
#pragma unroll
                for (int r = 0; r < 4; r++)
                    Cb[base + s + r] = (bf16)acc[mi][ni][r];
            }
        }
    }
}

// ---------------------------------------------------------------- flash attention
// Q: (b,h,s,64) bf16 (RoPE'd), K: (b,kv,s,64) bf16 (RoPE'd), Vt: (b,kv,64,s) bf16
// out attn: (b,s,h*64) bf16.  One block = 64 q rows (4 waves x 16), key tiles of 64.
#define LDF 72   // 144 B row stride, 16B aligned, 2-way-conflict-free

__global__ __launch_bounds__(256)
void flash_attn(const bf16* __restrict__ Q, const bf16* __restrict__ Kc,
                const bf16* __restrict__ Vt, bf16* __restrict__ Aout)
{
    __shared__ bf16 Ks[64 * LDF];
    __shared__ bf16 Vs[64 * LDF];
    __shared__ bf16 Ps[4 * 16 * LDF];

    const int tid  = threadIdx.x;
    const int lane = tid & 63;
    const int wave = tid >> 6;
    const int c = lane & 15, quad = lane >> 4;

    const int q0 = blockIdx.x * 64;
    const int bh = blockIdx.y;          // b*H + h
    const int b  = bh / H_SZ;
    const int h  = bh % H_SZ;
    const int kv = h >> 2;              // g = 4

    const bf16* Qp = Q  + (size_t)bh * S_SZ * 64;
    const bf16* Kp = Kc + (size_t)(b * KV_SZ + kv) * S_SZ * 64;
    const bf16* Vp = Vt + (size_t)(b * KV_SZ + kv) * 64 * S_SZ;

    // Q fragments (A-layout): row = lane&15, k = ks*32 + quad*8
    const int qrow = q0 + wave * 16 + c;
    bf16x8 aq[2];
    aq[0] = *(const bf16x8*)(Qp + (size_t)qrow * 64 + quad * 8);
    aq[1] = *(const bf16x8*)(Qp + (size_t)qrow * 64 + 32 + quad * 8);

    f32x4 o[4] = {};
    float m_st[4], l_st[4];
#pragma unroll
    for (int r = 0; r < 4; r++) { m_st[r] = -INFINITY; l_st[r] = 0.f; }

    int myrow[4];
#pragma unroll
    for (int r = 0; r < 4; r++) myrow[r] = q0 + wave * 16 + quad * 4 + r;

    bf16* Pw = Ps + wave * 16 * LDF;

    const int ktEnd = q0 >> 6;
    for (int kt = 0; kt <= ktEnd; kt++) {
        // ---- stage K tile (64x64) and Vt tile (64 d-rows x 64 s-cols)
        {
            int ch = tid;
            int row = ch >> 3, off = (ch & 7) * 8;
            *(uint4*)(Ks + row * LDF + off) = *(const uint4*)(Kp + (size_t)(kt * 64 + row) * 64 + off);
            *(uint4*)(Vs + row * LDF + off) = *(const uint4*)(Vp + (size_t)row * S_SZ + kt * 64 + off);
            ch = tid + 256;
            row = ch >> 3; off = (ch & 7) * 8;
            *(uint4*)(Ks + row * LDF + off) = *(const uint4*)(Kp + (size_t)(kt * 64 + row) * 64 + off);
            *(uint4*)(Vs + row * LDF + off) = *(const uint4*)(Vp + (size_t)row * S_SZ + kt * 64 + off);
        }
        __syncthreads();

        // ---- scores = Q K^T  (16 q-rows x 64 keys per wave)
        f32x4 sc[4] = {};
#pragma unroll
        for (int ks = 0; ks < 2; ks++)
#pragma unroll
            for (int ni = 0; ni < 4; ni++) {
                bf16x8 bk = *(const bf16x8*)(Ks + (ni * 16 + c) * LDF + ks * 32 + quad * 8);
                sc[ni] = __builtin_amdgcn_mfma_f32_16x16x32_bf16(aq[ks], bk, sc[ni], 0, 0, 0);
            }

        // ---- mask + scale + online softmax
        float pv[4][4];
        float tmax[4];
#pragma unroll
        for (int r = 0; r < 4; r++) tmax[r] = -INFINITY;
#pragma unroll
        for (int ni = 0; ni < 4; ni++) {
            int col = kt * 64 + ni * 16 + c;
#pragma unroll
            for (int r = 0; r < 4; r++) {
                float v = sc[ni][r] * 0.125f;
                if (col > myrow[r]) v = -INFINITY;
                pv[ni][r] = v;
                tmax[r] = fmaxf(tmax[r], v);
            }
        }
#pragma unroll
        for (int r = 0; r < 4; r++) {
#pragma unroll
            for (int off = 1; off < 16; off <<= 1)
                tmax[r] = fmaxf(tmax[r], __shfl_xor(tmax[r], off));
            float mnew  = fmaxf(m_st[r], tmax[r]);
            float alpha = __expf(m_st[r] - mnew);
            m_st[r] = mnew;
            float rs = 0.f;
#pragma unroll
            for (int ni = 0; ni < 4; ni++) {
                float p = __expf(pv[ni][r] - mnew);
                pv[ni][r] = p;
                rs += p;
            }
#pragma unroll
            for (int off = 1; off < 16; off <<= 1)
                rs += __shfl_xor(rs, off);
            l_st[r] = l_st[r] * alpha + rs;
#pragma unroll
            for (int ni = 0; ni < 4; ni++) o[ni][r] *= alpha;
        }

        // ---- P (C-layout) -> LDS -> A-layout
#pragma unroll
        for (int ni = 0; ni < 4; ni++)
#pragma unroll
            for (int r = 0; r < 4; r++)
                Pw[(quad * 4 + r) * LDF + ni * 16 + c] = (bf16)pv[ni][r];

        // ---- O += P Vt^T
#pragma unroll
        for (int ks = 0; ks < 2; ks++) {
            bf16x8 ap = *(const bf16x8*)(Pw + c * LDF + ks * 32 + quad * 8);
#pragma unroll
            for (int ni = 0; ni < 4; ni++) {
                bf16x8 bv = *(const bf16x8*)(Vs + (ni * 16 + c) * LDF + ks * 32 + quad * 8);
                o[ni] = __builtin_amdgcn_mfma_f32_16x16x32_bf16(ap, bv, o[ni], 0, 0, 0);
            }
        }
        __syncthreads();
    }

    // ---- epilogue: normalize and store (b, s, h*64+d) bf16
    float inv_l[4];
#pragma unroll
    for (int r = 0; r < 4; r++) inv_l[r] = 1.f / l_st[r];
#pragma unroll
    for (int ni = 0; ni < 4; ni++) {
        int d = ni * 16 + c;
#pragma unroll
        for (int r = 0; r < 4; r++) {
            int row = myrow[r];
            Aout[((size_t)(b * S_SZ + row)) * D_SZ + h * 64 + d] = (bf16)(o[ni][r] * inv_l[r]);
        }
    }
}

// ---------------------------------------------------------------- launcher
extern "C" void kernel_launch(void* const* d_in, const int* in_sizes, int n_in,
                              void* d_out, int out_size, void* d_ws, size_t ws_size,
                              hipStream_t stream) {
    const float* x    = (const float*)d_in[0];
    const float* cosp = (const float*)d_in[1];
    const float* sinp = (const float*)d_in[2];
    const float* Wq   = (const float*)d_in[3];
    const float* Wk   = (const float*)d_in[4];
    const float* Wv   = (const float*)d_in[5];
    const float* Wo   = (const float*)d_in[6];
    float* out = (float*)d_out;

    const int M = M_SZ;          // 4096
    const int D = D_SZ;          // 2048
    const int NKV = KV_SZ * HD_SZ; // 512

    // workspace layout (bf16 elems)
    bf16* xb   = (bf16*)d_ws;                    // M*D
    bf16* wqb  = xb  + (size_t)M * D;            // D*D
    bf16* wkb  = wqb + (size_t)D * D;            // NKV*D
    bf16* wvb  = wkb + (size_t)NKV * D;          // NKV*D
    bf16* Qb   = wvb + (size_t)NKV * D;          // M*D  (b,h,s,64)
    bf16* Kb   = Qb  + (size_t)M * D;            // B*KV*S*64 (b,kv,s,64)
    bf16* Vtb  = Kb  + (size_t)B_SZ * KV_SZ * S_SZ * 64; // (b,kv,64,s)
    bf16* attn = xb;    // alias: x dead after V GEMM
    bf16* wob  = wqb;   // alias: Wq_bf16 dead after Q GEMM

    // conversions
    cvt_f32_bf16<<<(M * D / 4 + 255) / 256, 256, 0, stream>>>(x, xb, M * D / 4);
    cvt_f32_bf16<<<(D * D / 4 + 255) / 256, 256, 0, stream>>>(Wq, wqb, D * D / 4);
    cvt_f32_bf16<<<(NKV * D / 4 + 255) / 256, 256, 0, stream>>>(Wk, wkb, NKV * D / 4);
    cvt_f32_bf16<<<(NKV * D / 4 + 255) / 256, 256, 0, stream>>>(Wv, wvb, NKV * D / 4);

    // Q = x Wq^T + RoPE -> (b,h,s,64)
    gemm_bt<<<dim3(D / 128, M / 128), 256, 0, stream>>>(xb, wqb, nullptr, Qb, cosp, sinp, M, D, D, 1);
    // Wo conversion reuses wqb space (after Q GEMM in stream order)
    cvt_f32_bf16<<<(D * D / 4 + 255) / 256, 256, 0, stream>>>(Wo, wob, D * D / 4);
    // K = x Wk^T + RoPE -> (b,kv,s,64)
    gemm_bt<<<dim3(NKV / 128, M / 128), 256, 0, stream>>>(xb, wkb, nullptr, Kb, cosp, sinp, M, NKV, D, 1);
    // V = x Wv^T -> transposed (b,kv,64,s)
    gemm_bt<<<dim3(NKV / 128, M / 128), 256, 0, stream>>>(xb, wvb, nullptr, Vtb, nullptr, nullptr, M, NKV, D, 2);

    // flash attention -> attn (b,s,2048) bf16 (overwrites xb)
    flash_attn<<<dim3(S_SZ / 64, B_SZ * H_SZ), 256, 0, stream>>>(Qb, Kb, Vtb, attn);

    // out = attn Wo^T (fp32)
    gemm_bt<<<dim3(D / 128, M / 128), 256, 0, stream>>>(attn, wob, out, nullptr, nullptr, nullptr, M, D, D, 0);
}